// Round 1
// baseline (83.253 us; speedup 1.0000x reference)
//
#include <hip/hip_runtime.h>
#include <cstddef>

#define BB 2
#define HH 64
#define WW 64
#define CC 128
#define NHH 4
#define KK 7
#define HD 32
#define SCALE 0.17677669529663687f   // 32^-0.5

// ---------------------------------------------------------------------------
// Generic GEMM: C[M x N] = A[M x 128] @ W[128 x N] + bias, optional q-scale
// BM=64, BN=64, K processed in two halves of 64. 256 threads, 4x4 micro-tile.
// ---------------------------------------------------------------------------
__global__ __launch_bounds__(256) void gemm_bias_kernel(
    const float* __restrict__ A,    // M x 128 row-major
    const float* __restrict__ Wm,   // 128 x N row-major
    const float* __restrict__ bias, // N
    float* __restrict__ C,          // M x N row-major
    int N, int scale_q)
{
    __shared__ float As[64][68];   // +4 pad: 2-way-free scalar reads, aligned f4 writes
    __shared__ float Bs[64][64];

    const int m0 = blockIdx.x * 64;
    const int n0 = blockIdx.y * 64;
    const int tid = threadIdx.x;
    const int tx = tid & 15;       // col group (4 cols)
    const int ty = tid >> 4;       // row group (4 rows)

    float acc[4][4] = {};

    for (int k0 = 0; k0 < 128; k0 += 64) {
        __syncthreads();
        // stage A half-tile: 64 rows x 64 cols = 1024 float4, 4 per thread
        #pragma unroll
        for (int it = 0; it < 4; ++it) {
            int i = tid + it * 256;
            int r = i >> 4, c = i & 15;
            float4 v = *(const float4*)(A + (size_t)(m0 + r) * 128 + k0 + c * 4);
            *((float4*)&As[r][c * 4]) = v;
        }
        // stage W half-tile: rows k0..k0+63, cols n0..n0+63
        #pragma unroll
        for (int it = 0; it < 4; ++it) {
            int i = tid + it * 256;
            int r = i >> 4, c = i & 15;
            float4 v = *(const float4*)(Wm + (size_t)(k0 + r) * N + n0 + c * 4);
            *((float4*)&Bs[r][c * 4]) = v;
        }
        __syncthreads();

        #pragma unroll 8
        for (int kk = 0; kk < 64; ++kk) {
            float a0 = As[ty * 4 + 0][kk];
            float a1 = As[ty * 4 + 1][kk];
            float a2 = As[ty * 4 + 2][kk];
            float a3 = As[ty * 4 + 3][kk];
            float4 bv = *(const float4*)&Bs[kk][tx * 4];
            acc[0][0] += a0 * bv.x; acc[0][1] += a0 * bv.y; acc[0][2] += a0 * bv.z; acc[0][3] += a0 * bv.w;
            acc[1][0] += a1 * bv.x; acc[1][1] += a1 * bv.y; acc[1][2] += a1 * bv.z; acc[1][3] += a1 * bv.w;
            acc[2][0] += a2 * bv.x; acc[2][1] += a2 * bv.y; acc[2][2] += a2 * bv.z; acc[2][3] += a2 * bv.w;
            acc[3][0] += a3 * bv.x; acc[3][1] += a3 * bv.y; acc[3][2] += a3 * bv.z; acc[3][3] += a3 * bv.w;
        }
    }

    // epilogue: bias (+ optional q scale on columns < 128 of qkv output)
    float4 bb = *(const float4*)(bias + n0 + tx * 4);
    const bool do_scale = scale_q && (n0 < 128);   // tile fully inside q columns (n0 % 64 == 0)
    #pragma unroll
    for (int r = 0; r < 4; ++r) {
        float4 o;
        o.x = acc[r][0] + bb.x;
        o.y = acc[r][1] + bb.y;
        o.z = acc[r][2] + bb.z;
        o.w = acc[r][3] + bb.w;
        if (do_scale) { o.x *= SCALE; o.y *= SCALE; o.z *= SCALE; o.w *= SCALE; }
        *((float4*)&C[(size_t)(m0 + ty * 4 + r) * N + n0 + tx * 4]) = o;
    }
}

// ---------------------------------------------------------------------------
// Neighborhood attention: 1 block per pixel, 4 waves (1 head each).
// Lane j<49 owns neighbor (p,q)=(j/7,j%7): QK dot + bias -> shuffle softmax.
// Lanes 0..31 then accumulate PV (coalesced V reads), write attn_out.
// qkv layout per pixel: [q(128) | k(128) | v(128)], q already scaled.
// ---------------------------------------------------------------------------
__global__ __launch_bounds__(256) void natten_kernel(
    const float* __restrict__ qkv,      // (B*H*W) x 384
    const float* __restrict__ rpb,      // 4 x 13 x 13
    float* __restrict__ attn_out)       // (B*H*W) x 128
{
    const int pix = blockIdx.x;
    const int b = pix >> 12;
    const int h = (pix >> 6) & 63;
    const int w = pix & 63;
    const int tid = threadIdx.x;
    const int head = tid >> 6;
    const int lane = tid & 63;

    __shared__ float q_lds[4][32];
    __shared__ float attn_lds[4][49];

    if (tid < 128) {
        q_lds[tid >> 5][tid & 31] = qkv[(size_t)pix * 384 + tid];
    }
    __syncthreads();

    int hs = h - 3; hs = hs < 0 ? 0 : (hs > 57 ? 57 : hs);
    int ws = w - 3; ws = ws < 0 ? 0 : (ws > 57 ? 57 : ws);

    float logit = -1e30f;
    if (lane < 49) {
        int p = lane / 7;
        int qq = lane - p * 7;
        int gh = hs + p, gw = ws + qq;
        const float* kp = qkv + (size_t)((b << 12) + (gh << 6) + gw) * 384 + 128 + head * 32;
        const float4* kp4 = (const float4*)kp;
        const float4* qp4 = (const float4*)&q_lds[head][0];
        float s = 0.f;
        #pragma unroll
        for (int d4 = 0; d4 < 8; ++d4) {
            float4 kv = kp4[d4];
            float4 qv = qp4[d4];
            s += kv.x * qv.x + kv.y * qv.y + kv.z * qv.z + kv.w * qv.w;
        }
        logit = s + rpb[head * 169 + (gh - h + 6) * 13 + (gw - w + 6)];
    }

    // wave softmax over 49 active lanes
    float m = logit;
    #pragma unroll
    for (int off = 32; off; off >>= 1) m = fmaxf(m, __shfl_xor(m, off));
    float e = (lane < 49) ? __expf(logit - m) : 0.f;
    float ssum = e;
    #pragma unroll
    for (int off = 32; off; off >>= 1) ssum += __shfl_xor(ssum, off);
    float a = e / ssum;

    if (lane < 49) attn_lds[head][lane] = a;
    __syncthreads();

    if (lane < 32) {
        const float* vb = qkv + (size_t)(b << 12) * 384 + 256 + head * 32 + lane;
        float o = 0.f;
        #pragma unroll
        for (int j = 0; j < 49; ++j) {
            int p = j / 7, qq = j - p * 7;           // compile-time (unrolled)
            o += attn_lds[head][j] * vb[(size_t)(((hs + p) << 6) + (ws + qq)) * 384];
        }
        attn_out[(size_t)pix * 128 + head * 32 + lane] = o;
    }
}

extern "C" void kernel_launch(void* const* d_in, const int* in_sizes, int n_in,
                              void* d_out, int out_size, void* d_ws, size_t ws_size,
                              hipStream_t stream)
{
    const float* x      = (const float*)d_in[0];
    const float* w_qkv  = (const float*)d_in[1];
    const float* b_qkv  = (const float*)d_in[2];
    const float* rpb    = (const float*)d_in[3];
    const float* w_proj = (const float*)d_in[4];
    const float* b_proj = (const float*)d_in[5];
    float* out = (float*)d_out;

    const int M = BB * HH * WW;             // 8192
    float* qkv      = (float*)d_ws;         // M x 384
    float* attn_out = qkv + (size_t)M * 384;// M x 128

    // 1) qkv = x @ w_qkv + b_qkv, q-part scaled
    gemm_bias_kernel<<<dim3(M / 64, 384 / 64), 256, 0, stream>>>(
        x, w_qkv, b_qkv, qkv, 384, 1);

    // 2) neighborhood attention
    natten_kernel<<<M, 256, 0, stream>>>(qkv, rpb, attn_out);

    // 3) out = attn_out @ w_proj + b_proj
    gemm_bias_kernel<<<dim3(M / 64, 128 / 64), 256, 0, stream>>>(
        attn_out, w_proj, b_proj, out, 128, 0);
}

// Round 2
// 51.388 us; speedup vs baseline: 1.6201x; 1.6201x over previous
//
#include <hip/hip_runtime.h>
#include <cstddef>

#define BB 2
#define HH 64
#define WW 64
#define CC 128
#define NHH 4
#define KK 7
#define HD 32
#define SCALE 0.17677669529663687f   // 32^-0.5

// natten tile geometry
#define TQH 4
#define TQW 16
#define HALO_H 10
#define HALO_W 22
#define NPIX (HALO_H * HALO_W)   // 220

// ---------------------------------------------------------------------------
// Generic GEMM: C[M x N] = A[M x 128] @ W[128 x N] + bias, optional q-scale
// BM=64, BN=64, K processed in two halves of 64. 256 threads, 4x4 micro-tile.
// ---------------------------------------------------------------------------
__global__ __launch_bounds__(256) void gemm_bias_kernel(
    const float* __restrict__ A,    // M x 128 row-major
    const float* __restrict__ Wm,   // 128 x N row-major
    const float* __restrict__ bias, // N
    float* __restrict__ C,          // M x N row-major
    int N, int scale_q)
{
    __shared__ float As[64][68];
    __shared__ float Bs[64][64];

    const int m0 = blockIdx.x * 64;
    const int n0 = blockIdx.y * 64;
    const int tid = threadIdx.x;
    const int tx = tid & 15;
    const int ty = tid >> 4;

    float acc[4][4] = {};

    for (int k0 = 0; k0 < 128; k0 += 64) {
        __syncthreads();
        #pragma unroll
        for (int it = 0; it < 4; ++it) {
            int i = tid + it * 256;
            int r = i >> 4, c = i & 15;
            float4 v = *(const float4*)(A + (size_t)(m0 + r) * 128 + k0 + c * 4);
            *((float4*)&As[r][c * 4]) = v;
        }
        #pragma unroll
        for (int it = 0; it < 4; ++it) {
            int i = tid + it * 256;
            int r = i >> 4, c = i & 15;
            float4 v = *(const float4*)(Wm + (size_t)(k0 + r) * N + n0 + c * 4);
            *((float4*)&Bs[r][c * 4]) = v;
        }
        __syncthreads();

        #pragma unroll 8
        for (int kk = 0; kk < 64; ++kk) {
            float a0 = As[ty * 4 + 0][kk];
            float a1 = As[ty * 4 + 1][kk];
            float a2 = As[ty * 4 + 2][kk];
            float a3 = As[ty * 4 + 3][kk];
            float4 bv = *(const float4*)&Bs[kk][tx * 4];
            acc[0][0] += a0 * bv.x; acc[0][1] += a0 * bv.y; acc[0][2] += a0 * bv.z; acc[0][3] += a0 * bv.w;
            acc[1][0] += a1 * bv.x; acc[1][1] += a1 * bv.y; acc[1][2] += a1 * bv.z; acc[1][3] += a1 * bv.w;
            acc[2][0] += a2 * bv.x; acc[2][1] += a2 * bv.y; acc[2][2] += a2 * bv.z; acc[2][3] += a2 * bv.w;
            acc[3][0] += a3 * bv.x; acc[3][1] += a3 * bv.y; acc[3][2] += a3 * bv.z; acc[3][3] += a3 * bv.w;
        }
    }

    float4 bb = *(const float4*)(bias + n0 + tx * 4);
    const bool do_scale = scale_q && (n0 < 128);
    #pragma unroll
    for (int r = 0; r < 4; ++r) {
        float4 o;
        o.x = acc[r][0] + bb.x;
        o.y = acc[r][1] + bb.y;
        o.z = acc[r][2] + bb.z;
        o.w = acc[r][3] + bb.w;
        if (do_scale) { o.x *= SCALE; o.y *= SCALE; o.z *= SCALE; o.w *= SCALE; }
        *((float4*)&C[(size_t)(m0 + ty * 4 + r) * N + n0 + tx * 4]) = o;
    }
}

// ---------------------------------------------------------------------------
// Tiled neighborhood attention.
// Block = (batch b, head n, 4x16 query tile). 256 threads.
// Stage K+V for the 10x22 halo in LDS (XOR-swizzled float4 rows -> no bank
// conflicts), compute 64 queries x 49 neighbors from LDS.
// QK: thread = (query, t=tid&3), t covers neighbors j = t,t+4,..  Softmax
// across the 4 lanes of a query via shfl_xor(1/2). PV: thread = (query,
// dg=tid&3) accumulating dims [dg*8, dg*8+8).
// qkv layout per pixel: [q(128, pre-scaled) | k(128) | v(128)].
// ---------------------------------------------------------------------------
__global__ __launch_bounds__(256) void natten_tile_kernel(
    const float* __restrict__ qkv,      // (B*H*W) x 384
    const float* __restrict__ rpb,      // 4 x 13 x 13
    float* __restrict__ attn_out)       // (B*H*W) x 128
{
    const int head = blockIdx.y;
    const int tidx = blockIdx.x;        // 0..127 : b(1) x th(16) x tw(4)
    const int b  = tidx >> 6;
    const int th = (tidx >> 2) & 15;
    const int tw = tidx & 3;
    const int h0 = th * TQH, w0 = tw * TQW;
    const int ho = max(0, h0 - 3), wo = max(0, w0 - 3);

    __shared__ float K_s[NPIX][32];
    __shared__ float V_s[NPIX][32];
    __shared__ float attn_s[64][50];
    __shared__ float rpb_s[169];

    const int tid = threadIdx.x;

    // per-thread query setup (also used to issue Q loads early)
    const int q  = tid >> 2;
    const int t4 = tid & 3;
    const int qh = h0 + (q >> 4), qw = w0 + (q & 15);
    const int hs = min(max(qh - 3, 0), HH - KK);
    const int ws = min(max(qw - 3, 0), WW - KK);
    const int base_lp = (hs - ho) * HALO_W + (ws - wo);
    const int bh0 = hs - qh + 6, bw0 = ws - qw + 6;
    const size_t qpix = (size_t)((b << 12) + (qh << 6) + qw);

    float4 qv[8];
    #pragma unroll
    for (int d4 = 0; d4 < 8; ++d4)
        qv[d4] = *(const float4*)(qkv + qpix * 384 + head * 32 + d4 * 4);

    if (tid < 169) rpb_s[tid] = rpb[head * 169 + tid];

    // stage K and V halos: 220 pixels x 8 float4 each
    #pragma unroll
    for (int it = 0; it < 7; ++it) {
        int idx = tid + it * 256;
        if (idx < NPIX * 8) {
            int pix = idx >> 3, d4 = idx & 7;
            int r = pix / HALO_W, c = pix - r * HALO_W;
            int gh = min(ho + r, HH - 1), gw = min(wo + c, WW - 1);
            size_t gbase = (size_t)((b << 12) + (gh << 6) + gw) * 384 + head * 32;
            float4 kv = *(const float4*)(qkv + gbase + 128 + d4 * 4);
            float4 vv = *(const float4*)(qkv + gbase + 256 + d4 * 4);
            int pd = (d4 ^ (pix & 7)) * 4;
            *(float4*)&K_s[pix][pd] = kv;
            *(float4*)&V_s[pix][pd] = vv;
        }
    }
    __syncthreads();

    // ---- QK + bias ----
    float lg[13];
    #pragma unroll
    for (int i = 0; i < 13; ++i) {
        int j = t4 + i * 4;
        float s = -1e30f;
        if (j < 49) {
            int p = (j * 37) >> 8;          // exact j/7 for j<49
            int qq = j - p * 7;
            int lp = base_lp + p * HALO_W + qq;
            int sw = lp & 7;
            float acc = 0.f;
            #pragma unroll
            for (int d4 = 0; d4 < 8; ++d4) {
                float4 kk = *(const float4*)&K_s[lp][(d4 ^ sw) * 4];
                acc += kk.x * qv[d4].x + kk.y * qv[d4].y + kk.z * qv[d4].z + kk.w * qv[d4].w;
            }
            s = acc + rpb_s[(bh0 + p) * 13 + bw0 + qq];
        }
        lg[i] = s;
    }

    // ---- softmax over 49, split across 4 lanes of the query ----
    float m = lg[0];
    #pragma unroll
    for (int i = 1; i < 13; ++i) m = fmaxf(m, lg[i]);
    m = fmaxf(m, __shfl_xor(m, 1));
    m = fmaxf(m, __shfl_xor(m, 2));
    float ssum = 0.f;
    #pragma unroll
    for (int i = 0; i < 13; ++i) {
        int j = t4 + i * 4;
        lg[i] = (j < 49) ? __expf(lg[i] - m) : 0.f;
        ssum += lg[i];
    }
    ssum += __shfl_xor(ssum, 1);
    ssum += __shfl_xor(ssum, 2);
    float inv = 1.f / ssum;
    #pragma unroll
    for (int i = 0; i < 13; ++i) {
        int j = t4 + i * 4;
        if (j < 49) attn_s[q][j] = lg[i] * inv;
    }
    __syncthreads();

    // ---- PV: thread accumulates dims [dg*8, dg*8+8) of its query ----
    const int dg = t4;
    float4 o0 = {0.f, 0.f, 0.f, 0.f}, o1 = {0.f, 0.f, 0.f, 0.f};
    #pragma unroll
    for (int j = 0; j < 49; ++j) {
        const int p = j / 7, qq = j % 7;      // compile-time (unrolled)
        int lp = base_lp + p * HALO_W + qq;
        float a = attn_s[q][j];
        int sw = lp & 7;
        float4 v0 = *(const float4*)&V_s[lp][((dg * 2) ^ sw) * 4];
        float4 v1 = *(const float4*)&V_s[lp][((dg * 2 + 1) ^ sw) * 4];
        o0.x += a * v0.x; o0.y += a * v0.y; o0.z += a * v0.z; o0.w += a * v0.w;
        o1.x += a * v1.x; o1.y += a * v1.y; o1.z += a * v1.z; o1.w += a * v1.w;
    }
    float* op = attn_out + qpix * 128 + head * 32 + dg * 8;
    *(float4*)op = o0;
    *(float4*)(op + 4) = o1;
}

extern "C" void kernel_launch(void* const* d_in, const int* in_sizes, int n_in,
                              void* d_out, int out_size, void* d_ws, size_t ws_size,
                              hipStream_t stream)
{
    const float* x      = (const float*)d_in[0];
    const float* w_qkv  = (const float*)d_in[1];
    const float* b_qkv  = (const float*)d_in[2];
    const float* rpb    = (const float*)d_in[3];
    const float* w_proj = (const float*)d_in[4];
    const float* b_proj = (const float*)d_in[5];
    float* out = (float*)d_out;

    const int M = BB * HH * WW;             // 8192
    float* qkv      = (float*)d_ws;         // M x 384
    float* attn_out = qkv + (size_t)M * 384;// M x 128

    // 1) qkv = x @ w_qkv + b_qkv, q-part scaled
    gemm_bias_kernel<<<dim3(M / 64, 384 / 64), 256, 0, stream>>>(
        x, w_qkv, b_qkv, qkv, 384, 1);

    // 2) tiled neighborhood attention: grid = (b x th x tw, head)
    natten_tile_kernel<<<dim3(128, NHH), 256, 0, stream>>>(qkv, rpb, attn_out);

    // 3) out = attn_out @ w_proj + b_proj
    gemm_bias_kernel<<<dim3(M / 64, 128 / 64), 256, 0, stream>>>(
        attn_out, w_proj, b_proj, out, 128, 0);
}

// Round 3
// 45.276 us; speedup vs baseline: 1.8388x; 1.1350x over previous
//
#include <hip/hip_runtime.h>
#include <hip/hip_bf16.h>
#include <cstddef>

#define BB 2
#define HH 64
#define WW 64
#define CC 128
#define NHH 4
#define KK 7
#define HD 32
#define SCALE 0.17677669529663687f   // 32^-0.5

// natten tile geometry
#define TQH 4
#define TQW 16
#define HALO_H 10
#define HALO_W 22
#define NPIX (HALO_H * HALO_W)   // 220

typedef short short8 __attribute__((ext_vector_type(8)));
typedef float f32x4 __attribute__((ext_vector_type(4)));

__device__ inline ushort f2bf(float f) {
    union { __hip_bfloat16 b; ushort u; } cv;
    cv.b = __float2bfloat16(f);
    return cv.u;
}

// ---------------------------------------------------------------------------
// Weight transpose + f32->bf16: Wt[n][k] = W[k][n].
// Rows 0..383 from w_qkv (128x384), rows 384..511 from w_proj (128x128).
// ---------------------------------------------------------------------------
__global__ __launch_bounds__(128) void cvt_w_kernel(
    const float* __restrict__ w_qkv, const float* __restrict__ w_proj,
    ushort* __restrict__ Wt)
{
    const int n = blockIdx.x;
    const int k = threadIdx.x;
    float v = (n < 384) ? w_qkv[(size_t)k * 384 + n]
                        : w_proj[(size_t)k * 128 + (n - 384)];
    Wt[(size_t)n * 128 + k] = f2bf(v);
}

// ---------------------------------------------------------------------------
// MFMA GEMM: C[M x N] = A[M x 128] @ Wt^T + bias. Wt is [n][k] bf16.
// Tile BM x 128, K=128 fully staged in LDS (bf16, XOR-swizzled 16B chunks).
// 4 waves in 2x2 quadrants; 16x16x32 bf16 MFMA; f32 accum; f32 output.
// CVT_A: A is f32 (convert during staging); else A is bf16 (ushort).
// ---------------------------------------------------------------------------
template<int BM, bool CVT_A>
__global__ __launch_bounds__(256) void mfma_gemm_kernel(
    const void* __restrict__ Aptr,
    const ushort* __restrict__ Bt,     // [>=n0+128][128] bf16, n-major
    const float* __restrict__ bias,    // N
    float* __restrict__ C,             // M x N f32
    int N, int scale_q)
{
    constexpr int BN = 128;
    constexpr int FM = BM / 32;        // frags per wave in M
    constexpr int FN = BN / 32;        // frags per wave in N (=4)

    __shared__ ushort As[BM * 128];
    __shared__ ushort Bs[BN * 128];

    const int m0 = blockIdx.x * BM;
    const int n0 = blockIdx.y * BN;
    const int tid = threadIdx.x;

    // ---- stage A (BM x 128) ----
    #pragma unroll
    for (int L = tid; L < BM * 16; L += 256) {
        int r = L >> 4, c = L & 15;
        int cs = c ^ (r & 7);
        if (CVT_A) {
            const float* src = (const float*)Aptr + (size_t)(m0 + r) * 128 + c * 8;
            float4 v0 = *(const float4*)src;
            float4 v1 = *(const float4*)(src + 4);
            union { ushort s[8]; uint4 q; } u;
            u.s[0] = f2bf(v0.x); u.s[1] = f2bf(v0.y); u.s[2] = f2bf(v0.z); u.s[3] = f2bf(v0.w);
            u.s[4] = f2bf(v1.x); u.s[5] = f2bf(v1.y); u.s[6] = f2bf(v1.z); u.s[7] = f2bf(v1.w);
            *(uint4*)&As[r * 128 + cs * 8] = u.q;
        } else {
            uint4 v = *(const uint4*)((const ushort*)Aptr + (size_t)(m0 + r) * 128 + c * 8);
            *(uint4*)&As[r * 128 + cs * 8] = v;
        }
    }
    // ---- stage B (BN x 128, already bf16 n-major) ----
    #pragma unroll
    for (int L = tid; L < BN * 16; L += 256) {
        int r = L >> 4, c = L & 15;
        int cs = c ^ (r & 7);
        uint4 v = *(const uint4*)(Bt + (size_t)(n0 + r) * 128 + c * 8);
        *(uint4*)&Bs[r * 128 + cs * 8] = v;
    }
    __syncthreads();

    const int wid = tid >> 6, lane = tid & 63;
    const int wr = wid >> 1, wc = wid & 1;
    const int mr = wr * (BM / 2);      // quadrant row base (within tile)
    const int nr = wc * (BN / 2);      // quadrant col base
    const int l15 = lane & 15, l4 = lane >> 4;

    f32x4 acc[FM][FN] = {};

    #pragma unroll
    for (int ks = 0; ks < 4; ++ks) {
        short8 af[FM], bf[FN];
        #pragma unroll
        for (int fm = 0; fm < FM; ++fm) {
            int row = mr + fm * 16 + l15;
            int c = (ks * 4 + l4) ^ (row & 7);
            af[fm] = *(const short8*)&As[row * 128 + c * 8];
        }
        #pragma unroll
        for (int fn = 0; fn < FN; ++fn) {
            int row = nr + fn * 16 + l15;
            int c = (ks * 4 + l4) ^ (row & 7);
            bf[fn] = *(const short8*)&Bs[row * 128 + c * 8];
        }
        #pragma unroll
        for (int fm = 0; fm < FM; ++fm)
            #pragma unroll
            for (int fn = 0; fn < FN; ++fn)
                acc[fm][fn] = __builtin_amdgcn_mfma_f32_16x16x32_bf16(
                    af[fm], bf[fn], acc[fm][fn], 0, 0, 0);
    }

    // ---- epilogue: bias (+ q scale), f32 store ----
    #pragma unroll
    for (int fn = 0; fn < FN; ++fn) {
        int col = n0 + nr + fn * 16 + l15;
        float bc = bias[col];
        float sc = (scale_q && (n0 + nr + fn * 16) < 128) ? SCALE : 1.0f;
        #pragma unroll
        for (int fm = 0; fm < FM; ++fm) {
            #pragma unroll
            for (int reg = 0; reg < 4; ++reg) {
                int row = m0 + mr + fm * 16 + l4 * 4 + reg;
                C[(size_t)row * N + col] = (acc[fm][fn][reg] + bc) * sc;
            }
        }
    }
}

// ---------------------------------------------------------------------------
// Tiled neighborhood attention (unchanged from round 2 except bf16 output).
// ---------------------------------------------------------------------------
__global__ __launch_bounds__(256) void natten_tile_kernel(
    const float* __restrict__ qkv,      // (B*H*W) x 384, q pre-scaled
    const float* __restrict__ rpb,      // 4 x 13 x 13
    ushort* __restrict__ attn_out)      // (B*H*W) x 128 bf16
{
    const int head = blockIdx.y;
    const int tidx = blockIdx.x;        // 0..127 : b(1) x th(16) x tw(4)
    const int b  = tidx >> 6;
    const int th = (tidx >> 2) & 15;
    const int tw = tidx & 3;
    const int h0 = th * TQH, w0 = tw * TQW;
    const int ho = max(0, h0 - 3), wo = max(0, w0 - 3);

    __shared__ float K_s[NPIX][32];
    __shared__ float V_s[NPIX][32];
    __shared__ float attn_s[64][50];
    __shared__ float rpb_s[169];

    const int tid = threadIdx.x;

    const int q  = tid >> 2;
    const int t4 = tid & 3;
    const int qh = h0 + (q >> 4), qw = w0 + (q & 15);
    const int hs = min(max(qh - 3, 0), HH - KK);
    const int ws = min(max(qw - 3, 0), WW - KK);
    const int base_lp = (hs - ho) * HALO_W + (ws - wo);
    const int bh0 = hs - qh + 6, bw0 = ws - qw + 6;
    const size_t qpix = (size_t)((b << 12) + (qh << 6) + qw);

    float4 qv[8];
    #pragma unroll
    for (int d4 = 0; d4 < 8; ++d4)
        qv[d4] = *(const float4*)(qkv + qpix * 384 + head * 32 + d4 * 4);

    if (tid < 169) rpb_s[tid] = rpb[head * 169 + tid];

    #pragma unroll
    for (int it = 0; it < 7; ++it) {
        int idx = tid + it * 256;
        if (idx < NPIX * 8) {
            int pix = idx >> 3, d4 = idx & 7;
            int r = pix / HALO_W, c = pix - r * HALO_W;
            int gh = min(ho + r, HH - 1), gw = min(wo + c, WW - 1);
            size_t gbase = (size_t)((b << 12) + (gh << 6) + gw) * 384 + head * 32;
            float4 kv = *(const float4*)(qkv + gbase + 128 + d4 * 4);
            float4 vv = *(const float4*)(qkv + gbase + 256 + d4 * 4);
            int pd = (d4 ^ (pix & 7)) * 4;
            *(float4*)&K_s[pix][pd] = kv;
            *(float4*)&V_s[pix][pd] = vv;
        }
    }
    __syncthreads();

    // ---- QK + bias ----
    float lg[13];
    #pragma unroll
    for (int i = 0; i < 13; ++i) {
        int j = t4 + i * 4;
        float s = -1e30f;
        if (j < 49) {
            int p = (j * 37) >> 8;          // exact j/7 for j<49
            int qq = j - p * 7;
            int lp = base_lp + p * HALO_W + qq;
            int sw = lp & 7;
            float acc = 0.f;
            #pragma unroll
            for (int d4 = 0; d4 < 8; ++d4) {
                float4 kk = *(const float4*)&K_s[lp][(d4 ^ sw) * 4];
                acc += kk.x * qv[d4].x + kk.y * qv[d4].y + kk.z * qv[d4].z + kk.w * qv[d4].w;
            }
            s = acc + rpb_s[(bh0 + p) * 13 + bw0 + qq];
        }
        lg[i] = s;
    }

    // ---- softmax over 49, split across 4 lanes of the query ----
    float m = lg[0];
    #pragma unroll
    for (int i = 1; i < 13; ++i) m = fmaxf(m, lg[i]);
    m = fmaxf(m, __shfl_xor(m, 1));
    m = fmaxf(m, __shfl_xor(m, 2));
    float ssum = 0.f;
    #pragma unroll
    for (int i = 0; i < 13; ++i) {
        int j = t4 + i * 4;
        lg[i] = (j < 49) ? __expf(lg[i] - m) : 0.f;
        ssum += lg[i];
    }
    ssum += __shfl_xor(ssum, 1);
    ssum += __shfl_xor(ssum, 2);
    float inv = 1.f / ssum;
    #pragma unroll
    for (int i = 0; i < 13; ++i) {
        int j = t4 + i * 4;
        if (j < 49) attn_s[q][j] = lg[i] * inv;
    }
    __syncthreads();

    // ---- PV: thread accumulates dims [dg*8, dg*8+8) of its query ----
    const int dg = t4;
    float4 o0 = {0.f, 0.f, 0.f, 0.f}, o1 = {0.f, 0.f, 0.f, 0.f};
    #pragma unroll
    for (int j = 0; j < 49; ++j) {
        const int p = j / 7, qq = j % 7;      // compile-time (unrolled)
        int lp = base_lp + p * HALO_W + qq;
        float a = attn_s[q][j];
        int sw = lp & 7;
        float4 v0 = *(const float4*)&V_s[lp][((dg * 2) ^ sw) * 4];
        float4 v1 = *(const float4*)&V_s[lp][((dg * 2 + 1) ^ sw) * 4];
        o0.x += a * v0.x; o0.y += a * v0.y; o0.z += a * v0.z; o0.w += a * v0.w;
        o1.x += a * v1.x; o1.y += a * v1.y; o1.z += a * v1.z; o1.w += a * v1.w;
    }
    union { ushort s[8]; uint4 q4; } u;
    u.s[0] = f2bf(o0.x); u.s[1] = f2bf(o0.y); u.s[2] = f2bf(o0.z); u.s[3] = f2bf(o0.w);
    u.s[4] = f2bf(o1.x); u.s[5] = f2bf(o1.y); u.s[6] = f2bf(o1.z); u.s[7] = f2bf(o1.w);
    *(uint4*)(attn_out + qpix * 128 + head * 32 + dg * 8) = u.q4;
}

extern "C" void kernel_launch(void* const* d_in, const int* in_sizes, int n_in,
                              void* d_out, int out_size, void* d_ws, size_t ws_size,
                              hipStream_t stream)
{
    const float* x      = (const float*)d_in[0];
    const float* w_qkv  = (const float*)d_in[1];
    const float* b_qkv  = (const float*)d_in[2];
    const float* rpb    = (const float*)d_in[3];
    const float* w_proj = (const float*)d_in[4];
    const float* b_proj = (const float*)d_in[5];
    float* out = (float*)d_out;

    const int M = BB * HH * WW;                  // 8192
    float*  qkv      = (float*)d_ws;             // M x 384 f32
    ushort* attn_bf  = (ushort*)(qkv + (size_t)M * 384);   // M x 128 bf16
    ushort* Wt       = attn_bf + (size_t)M * 128;          // 512 x 128 bf16
    ushort* Wt_proj  = Wt + (size_t)384 * 128;

    // 0) transpose+convert weights to bf16 [n][k]
    cvt_w_kernel<<<512, 128, 0, stream>>>(w_qkv, w_proj, Wt);

    // 1) qkv = x @ w_qkv + b_qkv (q part scaled), bf16 MFMA, f32 out
    mfma_gemm_kernel<64, true><<<dim3(M / 64, 3), 256, 0, stream>>>(
        x, Wt, b_qkv, qkv, 384, 1);

    // 2) tiled neighborhood attention -> bf16 attn_out
    natten_tile_kernel<<<dim3(128, NHH), 256, 0, stream>>>(qkv, rpb, attn_bf);

    // 3) out = attn_out @ w_proj + b_proj, bf16 MFMA, f32 out
    mfma_gemm_kernel<32, false><<<dim3(M / 32, 1), 256, 0, stream>>>(
        attn_bf, Wt_proj, b_proj, out, 128, 0);
}

// Round 4
// 42.702 us; speedup vs baseline: 1.9496x; 1.0603x over previous
//
#include <hip/hip_runtime.h>
#include <hip/hip_bf16.h>
#include <cstddef>

#define BB 2
#define HH 64
#define WW 64
#define CC 128
#define NHH 4
#define KK 7
#define HD 32
#define SCALE 0.17677669529663687f   // 32^-0.5

// natten tile geometry
#define TQH 4
#define TQW 16
#define HALO_H 10
#define HALO_W 22
#define NPIX (HALO_H * HALO_W)   // 220
#define KSTRIDE 40               // ushorts per LDS row (32 + 8 pad -> 80 B)

typedef short short8 __attribute__((ext_vector_type(8)));
typedef float f32x4 __attribute__((ext_vector_type(4)));

__device__ inline ushort f2bf(float f) {
    union { __hip_bfloat16 b; ushort u; } cv;
    cv.b = __float2bfloat16(f);
    return cv.u;
}
__device__ inline float bflo(uint u) { union { uint i; float f; } c; c.i = u << 16; return c.f; }
__device__ inline float bfhi(uint u) { union { uint i; float f; } c; c.i = u & 0xffff0000u; return c.f; }

// ---------------------------------------------------------------------------
// Weight transpose + f32->bf16: Wt[n][k] = W[k][n].
// Rows 0..383 from w_qkv (128x384), rows 384..511 from w_proj (128x128).
// ---------------------------------------------------------------------------
__global__ __launch_bounds__(128) void cvt_w_kernel(
    const float* __restrict__ w_qkv, const float* __restrict__ w_proj,
    ushort* __restrict__ Wt)
{
    const int n = blockIdx.x;
    const int k = threadIdx.x;
    float v = (n < 384) ? w_qkv[(size_t)k * 384 + n]
                        : w_proj[(size_t)k * 128 + (n - 384)];
    Wt[(size_t)n * 128 + k] = f2bf(v);
}

// ---------------------------------------------------------------------------
// MFMA GEMM: C[M x N] = A[M x 128] @ Bt^T + bias. Bt is [n][k] bf16.
// Tile BM x BN, K=128 fully staged in LDS (bf16, XOR-swizzled 16B chunks).
// 4 waves in 2x2 quadrants; 16x16x32 bf16 MFMA; f32 accum.
// CVT_A: A is f32 (convert during staging), else bf16.
// OUT_BF16: C stored bf16, else f32.
// ---------------------------------------------------------------------------
template<int BM, int BN, bool CVT_A, bool OUT_BF16>
__global__ __launch_bounds__(256) void mfma_gemm_kernel(
    const void* __restrict__ Aptr,
    const ushort* __restrict__ Bt,     // [>=BN][128] bf16, n-major
    const float* __restrict__ bias,    // N
    void* __restrict__ Cptr,           // M x N
    int N, int scale_q)
{
    constexpr int FM = BM / 32;        // frags per wave in M
    constexpr int FN = BN / 32;        // frags per wave in N

    __shared__ ushort As[BM * 128];
    __shared__ ushort Bs[BN * 128];

    const int m0 = blockIdx.x * BM;
    const int n0 = blockIdx.y * BN;
    const int tid = threadIdx.x;

    // ---- stage A (BM x 128) ----
    #pragma unroll
    for (int L = tid; L < BM * 16; L += 256) {
        int r = L >> 4, c = L & 15;
        int cs = c ^ (r & 7);
        if (CVT_A) {
            const float* src = (const float*)Aptr + (size_t)(m0 + r) * 128 + c * 8;
            float4 v0 = *(const float4*)src;
            float4 v1 = *(const float4*)(src + 4);
            union { ushort s[8]; uint4 q; } u;
            u.s[0] = f2bf(v0.x); u.s[1] = f2bf(v0.y); u.s[2] = f2bf(v0.z); u.s[3] = f2bf(v0.w);
            u.s[4] = f2bf(v1.x); u.s[5] = f2bf(v1.y); u.s[6] = f2bf(v1.z); u.s[7] = f2bf(v1.w);
            *(uint4*)&As[r * 128 + cs * 8] = u.q;
        } else {
            uint4 v = *(const uint4*)((const ushort*)Aptr + (size_t)(m0 + r) * 128 + c * 8);
            *(uint4*)&As[r * 128 + cs * 8] = v;
        }
    }
    // ---- stage B (BN x 128) ----
    #pragma unroll
    for (int L = tid; L < BN * 16; L += 256) {
        int r = L >> 4, c = L & 15;
        int cs = c ^ (r & 7);
        uint4 v = *(const uint4*)(Bt + (size_t)(n0 + r) * 128 + c * 8);
        *(uint4*)&Bs[r * 128 + cs * 8] = v;
    }
    __syncthreads();

    const int wid = tid >> 6, lane = tid & 63;
    const int wr = wid >> 1, wc = wid & 1;
    const int mr = wr * (BM / 2);
    const int nr = wc * (BN / 2);
    const int l15 = lane & 15, l4 = lane >> 4;

    f32x4 acc[FM][FN] = {};

    #pragma unroll
    for (int ks = 0; ks < 4; ++ks) {
        short8 af[FM], bf[FN];
        #pragma unroll
        for (int fm = 0; fm < FM; ++fm) {
            int row = mr + fm * 16 + l15;
            int c = (ks * 4 + l4) ^ (row & 7);
            af[fm] = *(const short8*)&As[row * 128 + c * 8];
        }
        #pragma unroll
        for (int fn = 0; fn < FN; ++fn) {
            int row = nr + fn * 16 + l15;
            int c = (ks * 4 + l4) ^ (row & 7);
            bf[fn] = *(const short8*)&Bs[row * 128 + c * 8];
        }
        #pragma unroll
        for (int fm = 0; fm < FM; ++fm)
            #pragma unroll
            for (int fn = 0; fn < FN; ++fn)
                acc[fm][fn] = __builtin_amdgcn_mfma_f32_16x16x32_bf16(
                    af[fm], bf[fn], acc[fm][fn], 0, 0, 0);
    }

    // ---- epilogue: bias (+ q scale), store ----
    #pragma unroll
    for (int fn = 0; fn < FN; ++fn) {
        int col = n0 + nr + fn * 16 + l15;
        float bc = bias[col];
        float sc = (scale_q && (n0 + nr + fn * 16) < 128) ? SCALE : 1.0f;
        #pragma unroll
        for (int fm = 0; fm < FM; ++fm) {
            #pragma unroll
            for (int reg = 0; reg < 4; ++reg) {
                int row = m0 + mr + fm * 16 + l4 * 4 + reg;
                float v = (acc[fm][fn][reg] + bc) * sc;
                if (OUT_BF16) ((ushort*)Cptr)[(size_t)row * N + col] = f2bf(v);
                else          ((float*)Cptr)[(size_t)row * N + col] = v;
            }
        }
    }
}

// ---------------------------------------------------------------------------
// Tiled neighborhood attention, bf16 K/V in LDS (padded rows, ~2-way banks).
// Block = (batch b, head n, 4x16 query tile). 256 threads.
// qkv layout per pixel (bf16): [q(128, pre-scaled) | k(128) | v(128)].
// ---------------------------------------------------------------------------
__global__ __launch_bounds__(256) void natten_tile_kernel(
    const ushort* __restrict__ qkv,     // (B*H*W) x 384 bf16
    const float* __restrict__ rpb,      // 4 x 13 x 13
    ushort* __restrict__ attn_out)      // (B*H*W) x 128 bf16
{
    const int head = blockIdx.y;
    const int tidx = blockIdx.x;        // 0..127 : b(1) x th(16) x tw(4)
    const int b  = tidx >> 6;
    const int th = (tidx >> 2) & 15;
    const int tw = tidx & 3;
    const int h0 = th * TQH, w0 = tw * TQW;
    const int ho = max(0, h0 - 3), wo = max(0, w0 - 3);

    __shared__ ushort K_s[NPIX][KSTRIDE];
    __shared__ ushort V_s[NPIX][KSTRIDE];
    __shared__ float attn_s[64][50];
    __shared__ float rpb_s[169];

    const int tid = threadIdx.x;

    const int q  = tid >> 2;
    const int t4 = tid & 3;
    const int qh = h0 + (q >> 4), qw = w0 + (q & 15);
    const int hs = min(max(qh - 3, 0), HH - KK);
    const int ws = min(max(qw - 3, 0), WW - KK);
    const int base_lp = (hs - ho) * HALO_W + (ws - wo);
    const int bh0 = hs - qh + 6, bw0 = ws - qw + 6;
    const size_t qpix = (size_t)((b << 12) + (qh << 6) + qw);

    // Q into f32 regs (issued early to overlap staging)
    float qf[32];
    #pragma unroll
    for (int d4 = 0; d4 < 4; ++d4) {
        uint4 qu = *(const uint4*)(qkv + qpix * 384 + head * 32 + d4 * 8);
        qf[d4 * 8 + 0] = bflo(qu.x); qf[d4 * 8 + 1] = bfhi(qu.x);
        qf[d4 * 8 + 2] = bflo(qu.y); qf[d4 * 8 + 3] = bfhi(qu.y);
        qf[d4 * 8 + 4] = bflo(qu.z); qf[d4 * 8 + 5] = bfhi(qu.z);
        qf[d4 * 8 + 6] = bflo(qu.w); qf[d4 * 8 + 7] = bfhi(qu.w);
    }

    if (tid < 169) rpb_s[tid] = rpb[head * 169 + tid];

    // stage K and V halos: 220 pixels x 4 uint4 each
    #pragma unroll
    for (int it = 0; it < 4; ++it) {
        int idx = tid + it * 256;
        if (idx < NPIX * 4) {
            int pix = idx >> 2, d4 = idx & 3;
            int r = pix / HALO_W, c = pix - r * HALO_W;
            int gh = min(ho + r, HH - 1), gw = min(wo + c, WW - 1);
            const ushort* gp = qkv + (size_t)((b << 12) + (gh << 6) + gw) * 384 + head * 32 + d4 * 8;
            uint4 kv = *(const uint4*)(gp + 128);
            uint4 vv = *(const uint4*)(gp + 256);
            *(uint4*)&K_s[pix][d4 * 8] = kv;
            *(uint4*)&V_s[pix][d4 * 8] = vv;
        }
    }
    __syncthreads();

    // ---- QK + bias ----
    float lg[13];
    #pragma unroll
    for (int i = 0; i < 13; ++i) {
        int j = t4 + i * 4;
        float s = -1e30f;
        if (j < 49) {
            int p = (j * 37) >> 8;          // exact j/7 for j<49
            int qq = j - p * 7;
            int lp = base_lp + p * HALO_W + qq;
            const uint4* kr = (const uint4*)&K_s[lp][0];
            float acc = 0.f;
            #pragma unroll
            for (int d4 = 0; d4 < 4; ++d4) {
                uint4 ku = kr[d4];
                acc += bflo(ku.x) * qf[d4 * 8 + 0] + bfhi(ku.x) * qf[d4 * 8 + 1]
                     + bflo(ku.y) * qf[d4 * 8 + 2] + bfhi(ku.y) * qf[d4 * 8 + 3]
                     + bflo(ku.z) * qf[d4 * 8 + 4] + bfhi(ku.z) * qf[d4 * 8 + 5]
                     + bflo(ku.w) * qf[d4 * 8 + 6] + bfhi(ku.w) * qf[d4 * 8 + 7];
            }
            s = acc + rpb_s[(bh0 + p) * 13 + bw0 + qq];
        }
        lg[i] = s;
    }

    // ---- softmax over 49, split across 4 lanes of the query ----
    float m = lg[0];
    #pragma unroll
    for (int i = 1; i < 13; ++i) m = fmaxf(m, lg[i]);
    m = fmaxf(m, __shfl_xor(m, 1));
    m = fmaxf(m, __shfl_xor(m, 2));
    float ssum = 0.f;
    #pragma unroll
    for (int i = 0; i < 13; ++i) {
        int j = t4 + i * 4;
        lg[i] = (j < 49) ? __expf(lg[i] - m) : 0.f;
        ssum += lg[i];
    }
    ssum += __shfl_xor(ssum, 1);
    ssum += __shfl_xor(ssum, 2);
    float inv = 1.f / ssum;
    #pragma unroll
    for (int i = 0; i < 13; ++i) {
        int j = t4 + i * 4;
        if (j < 49) attn_s[q][j] = lg[i] * inv;
    }
    __syncthreads();

    // ---- PV: thread accumulates dims [dg*8, dg*8+8) of its query ----
    const int dg = t4;
    float o[8] = {};
    #pragma unroll
    for (int j = 0; j < 49; ++j) {
        const int p = j / 7, qq = j % 7;      // compile-time (unrolled)
        int lp = base_lp + p * HALO_W + qq;
        float a = attn_s[q][j];
        uint4 vu = *(const uint4*)&V_s[lp][dg * 8];
        o[0] += a * bflo(vu.x); o[1] += a * bfhi(vu.x);
        o[2] += a * bflo(vu.y); o[3] += a * bfhi(vu.y);
        o[4] += a * bflo(vu.z); o[5] += a * bfhi(vu.z);
        o[6] += a * bflo(vu.w); o[7] += a * bfhi(vu.w);
    }
    union { ushort s[8]; uint4 q4; } u;
    #pragma unroll
    for (int e = 0; e < 8; ++e) u.s[e] = f2bf(o[e]);
    *(uint4*)(attn_out + qpix * 128 + head * 32 + dg * 8) = u.q4;
}

extern "C" void kernel_launch(void* const* d_in, const int* in_sizes, int n_in,
                              void* d_out, int out_size, void* d_ws, size_t ws_size,
                              hipStream_t stream)
{
    const float* x      = (const float*)d_in[0];
    const float* w_qkv  = (const float*)d_in[1];
    const float* b_qkv  = (const float*)d_in[2];
    const float* rpb    = (const float*)d_in[3];
    const float* w_proj = (const float*)d_in[4];
    const float* b_proj = (const float*)d_in[5];
    float* out = (float*)d_out;

    const int M = BB * HH * WW;                       // 8192
    ushort* qkv_bf  = (ushort*)d_ws;                  // M x 384 bf16
    ushort* attn_bf = qkv_bf + (size_t)M * 384;       // M x 128 bf16
    ushort* Wt      = attn_bf + (size_t)M * 128;      // 512 x 128 bf16
    ushort* Wt_proj = Wt + (size_t)384 * 128;

    // 0) transpose+convert weights to bf16 [n][k]
    cvt_w_kernel<<<512, 128, 0, stream>>>(w_qkv, w_proj, Wt);

    // 1) qkv = x @ w_qkv + b_qkv (q scaled), bf16 out; single n-tile (BN=384)
    mfma_gemm_kernel<32, 384, true, true><<<dim3(M / 32, 1), 256, 0, stream>>>(
        x, Wt, b_qkv, qkv_bf, 384, 1);

    // 2) tiled neighborhood attention -> bf16 attn_out
    natten_tile_kernel<<<dim3(128, NHH), 256, 0, stream>>>(qkv_bf, rpb, attn_bf);

    // 3) out = attn_out @ w_proj + b_proj, f32 out
    mfma_gemm_kernel<32, 128, false, false><<<dim3(M / 32, 1), 256, 0, stream>>>(
        attn_bf, Wt_proj, b_proj, out, 128, 0);
}

// Round 5
// 33.530 us; speedup vs baseline: 2.4830x; 1.2736x over previous
//
#include <hip/hip_runtime.h>
#include <hip/hip_bf16.h>
#include <cstddef>

#define BB 2
#define HH 64
#define WW 64
#define SCALE 0.17677669529663687f   // 32^-0.5

// K2 tile geometry: 4x8 queries, all 4 heads per block
#define HALO_H 10
#define HALO_W 14
#define NPIX 140
#define NQ 32

typedef short short8 __attribute__((ext_vector_type(8)));
typedef float f32x4 __attribute__((ext_vector_type(4)));

__device__ inline ushort f2bf(float f) {
    union { __hip_bfloat16 b; ushort u; } cv;
    cv.b = __float2bfloat16(f);
    return cv.u;
}
__device__ inline float bflo(uint u) { union { uint i; float f; } c; c.i = u << 16; return c.f; }
__device__ inline float bfhi(uint u) { union { uint i; float f; } c; c.i = u & 0xffff0000u; return c.f; }

// ---------------------------------------------------------------------------
// K1: qkv = x @ w_qkv + b_qkv (q cols pre-scaled), bf16 out.
// BM=64 x BN=192, K=128 staged. B transposed f32->bf16 in-block (no cvt pass).
// Blocks (m, y=0) also emit Wp_t[n][k] = bf16(w_proj[k][n]) for K2.
// ---------------------------------------------------------------------------
__global__ __launch_bounds__(256) void qkv_gemm_kernel(
    const float* __restrict__ x, const float* __restrict__ w_qkv,
    const float* __restrict__ b_qkv, const float* __restrict__ w_proj,
    ushort* __restrict__ qkv, ushort* __restrict__ Wp_t)
{
    __shared__ ushort As[64 * 128];
    __shared__ ushort Bs[192 * 128];

    const int tid = threadIdx.x;
    const int m0 = blockIdx.x * 64;
    const int n0 = blockIdx.y * 192;

    // side job: transpose w_proj -> Wp_t (one n-row per (m,0) block)
    if (blockIdx.y == 0 && tid < 128)
        Wp_t[(size_t)blockIdx.x * 128 + tid] =
            f2bf(w_proj[(size_t)tid * 128 + blockIdx.x]);

    // stage A: 64x128, f32 -> bf16, chunk-XOR swizzle
    #pragma unroll
    for (int t = 0; t < 4; ++t) {
        int idx = tid + t * 256;
        int r = idx >> 4, c = idx & 15;
        const float* src = x + (size_t)(m0 + r) * 128 + c * 8;
        float4 v0 = *(const float4*)src;
        float4 v1 = *(const float4*)(src + 4);
        union { ushort s[8]; uint4 q; } u;
        u.s[0] = f2bf(v0.x); u.s[1] = f2bf(v0.y); u.s[2] = f2bf(v0.z); u.s[3] = f2bf(v0.w);
        u.s[4] = f2bf(v1.x); u.s[5] = f2bf(v1.y); u.s[6] = f2bf(v1.z); u.s[7] = f2bf(v1.w);
        *(uint4*)&As[r * 128 + (c ^ (r & 7)) * 8] = u.q;
    }
    // stage B: transpose w_qkv[k][n0..n0+192) -> Bs[n][k] bf16
    #pragma unroll
    for (int t = 0; t < 24; ++t) {
        int idx = tid + t * 256;           // 0..6143
        int r = idx / 48, c4 = idx - r * 48;
        float4 v = *(const float4*)(w_qkv + (size_t)r * 384 + n0 + c4 * 4);
        int kc = r >> 3, kp = r & 7;
        int n_ = c4 * 4;
        Bs[(n_ + 0) * 128 + ((kc ^ ((n_ + 0) & 7)) * 8) + kp] = f2bf(v.x);
        Bs[(n_ + 1) * 128 + ((kc ^ ((n_ + 1) & 7)) * 8) + kp] = f2bf(v.y);
        Bs[(n_ + 2) * 128 + ((kc ^ ((n_ + 2) & 7)) * 8) + kp] = f2bf(v.z);
        Bs[(n_ + 3) * 128 + ((kc ^ ((n_ + 3) & 7)) * 8) + kp] = f2bf(v.w);
    }
    __syncthreads();

    const int wid = tid >> 6, lane = tid & 63;
    const int l15 = lane & 15, l4 = lane >> 4;
    const int mr = (wid >> 1) * 32, nr = (wid & 1) * 96;

    f32x4 acc[2][6] = {};
    #pragma unroll
    for (int ks = 0; ks < 4; ++ks) {
        short8 af[2], bf[6];
        #pragma unroll
        for (int fm = 0; fm < 2; ++fm) {
            int row = mr + fm * 16 + l15;
            af[fm] = *(const short8*)&As[row * 128 + ((ks * 4 + l4) ^ (row & 7)) * 8];
        }
        #pragma unroll
        for (int fn = 0; fn < 6; ++fn) {
            int row = nr + fn * 16 + l15;
            bf[fn] = *(const short8*)&Bs[row * 128 + ((ks * 4 + l4) ^ (row & 7)) * 8];
        }
        #pragma unroll
        for (int fm = 0; fm < 2; ++fm)
            #pragma unroll
            for (int fn = 0; fn < 6; ++fn)
                acc[fm][fn] = __builtin_amdgcn_mfma_f32_16x16x32_bf16(
                    af[fm], bf[fn], acc[fm][fn], 0, 0, 0);
    }

    #pragma unroll
    for (int fn = 0; fn < 6; ++fn) {
        int colb = n0 + nr + fn * 16;
        int col = colb + l15;
        float bc = b_qkv[col];
        float sc = (colb < 128) ? SCALE : 1.0f;
        #pragma unroll
        for (int fm = 0; fm < 2; ++fm)
            #pragma unroll
            for (int reg = 0; reg < 4; ++reg) {
                int row = m0 + mr + fm * 16 + l4 * 4 + reg;
                qkv[(size_t)row * 384 + col] = f2bf((acc[fm][fn][reg] + bc) * sc);
            }
    }
}

// ---------------------------------------------------------------------------
// K2: fused neighborhood attention (all 4 heads) + output projection.
// Block = 4x8 query tile. Stage K/V halo (140 pix x 128 dims bf16, slot-XOR
// swizzle). Per head: 8 lanes/query QK + shuffle softmax + PV (attn via
// wave-local LDS). attn_out accumulated in LDS bf16, then MFMA proj with
// B-frags straight from L2-hot Wp_t. One block per CU (grid 256).
// ---------------------------------------------------------------------------
__global__ __launch_bounds__(256) void natten_proj_kernel(
    const ushort* __restrict__ qkv,     // (B*H*W) x 384 bf16, q pre-scaled
    const float* __restrict__ rpb,      // 4 x 13 x 13
    const ushort* __restrict__ Wp_t,    // 128 x 128 bf16, [n][k]
    const float* __restrict__ b_proj,   // 128
    float* __restrict__ out)            // (B*H*W) x 128 f32
{
    __shared__ ushort K_s[NPIX * 128];
    __shared__ ushort V_s[NPIX * 128];
    __shared__ ushort AO_s[NQ * 128];
    __shared__ float attn_s[NQ * 52];
    __shared__ float rpb_s[676];

    const int tid = threadIdx.x;
    // XCD-aware swizzle (256 % 8 == 0 -> bijective)
    const int bx = ((blockIdx.x & 7) << 5) | (blockIdx.x >> 3);
    const int b  = bx >> 7;
    const int th = (bx >> 3) & 15;
    const int tw = bx & 7;
    const int h0 = th * 4, w0 = tw * 8;
    const int ho = max(0, h0 - 3), wo = max(0, w0 - 3);

    // ---- stage K/V halo: 140 pix x 16 slots (8 bf16 each) ----
    #pragma unroll
    for (int t = 0; t < 9; ++t) {
        int idx = tid + t * 256;
        if (idx < NPIX * 16) {
            int pix = idx >> 4, s = idx & 15;
            int r = pix / HALO_W, c = pix - r * HALO_W;
            int gh = min(ho + r, HH - 1), gw = min(wo + c, WW - 1);
            const ushort* gp = qkv + (size_t)((b << 12) + (gh << 6) + gw) * 384 + s * 8;
            uint4 kv = *(const uint4*)(gp + 128);
            uint4 vv = *(const uint4*)(gp + 256);
            int so = (s ^ (pix & 7)) * 8;
            *(uint4*)&K_s[pix * 128 + so] = kv;
            *(uint4*)&V_s[pix * 128 + so] = vv;
        }
    }
    #pragma unroll
    for (int t = 0; t < 3; ++t) {
        int idx = tid + t * 256;
        if (idx < 676) rpb_s[idx] = rpb[idx];
    }

    // per-thread query mapping: 32 queries x 8 lanes
    const int q = tid >> 3, t8 = tid & 7;
    const int qh = h0 + (q >> 3), qw = w0 + (q & 7);
    const int hs = min(max(qh - 3, 0), HH - 7);
    const int ws = min(max(qw - 3, 0), WW - 7);
    const int base_lp = (hs - ho) * HALO_W + (ws - wo);
    const int bh0 = hs - qh + 6, bw0 = ws - qw + 6;
    const size_t qpix = (size_t)((b << 12) + (qh << 6) + qw);

    __syncthreads();

    for (int hd = 0; hd < 4; ++hd) {
        // Q -> f32 regs
        float qf[32];
        #pragma unroll
        for (int d4 = 0; d4 < 4; ++d4) {
            uint4 qu = *(const uint4*)(qkv + qpix * 384 + hd * 32 + d4 * 8);
            qf[d4*8+0] = bflo(qu.x); qf[d4*8+1] = bfhi(qu.x);
            qf[d4*8+2] = bflo(qu.y); qf[d4*8+3] = bfhi(qu.y);
            qf[d4*8+4] = bflo(qu.z); qf[d4*8+5] = bfhi(qu.z);
            qf[d4*8+6] = bflo(qu.w); qf[d4*8+7] = bfhi(qu.w);
        }

        // QK + bias: lane t8 handles j = t8, t8+8, ...
        float lg[7];
        #pragma unroll
        for (int i = 0; i < 7; ++i) {
            int j = t8 + i * 8;
            float s = -1e30f;
            if (j < 49) {
                int p = (j * 37) >> 8;        // exact j/7 for j<=48
                int qq = j - p * 7;
                int lp = base_lp + p * HALO_W + qq;
                float a = 0.f;
                #pragma unroll
                for (int d4 = 0; d4 < 4; ++d4) {
                    uint4 ku = *(const uint4*)&K_s[lp * 128 + ((hd*4 + d4) ^ (lp & 7)) * 8];
                    a += bflo(ku.x)*qf[d4*8+0] + bfhi(ku.x)*qf[d4*8+1]
                       + bflo(ku.y)*qf[d4*8+2] + bfhi(ku.y)*qf[d4*8+3]
                       + bflo(ku.z)*qf[d4*8+4] + bfhi(ku.z)*qf[d4*8+5]
                       + bflo(ku.w)*qf[d4*8+6] + bfhi(ku.w)*qf[d4*8+7];
                }
                s = a + rpb_s[hd * 169 + (bh0 + p) * 13 + (bw0 + qq)];
            }
            lg[i] = s;
        }

        // softmax across the query's 8 lanes
        float m = lg[0];
        #pragma unroll
        for (int i = 1; i < 7; ++i) m = fmaxf(m, lg[i]);
        m = fmaxf(m, __shfl_xor(m, 1));
        m = fmaxf(m, __shfl_xor(m, 2));
        m = fmaxf(m, __shfl_xor(m, 4));
        float ssum = 0.f;
        #pragma unroll
        for (int i = 0; i < 7; ++i) {
            int j = t8 + i * 8;
            lg[i] = (j < 49) ? __expf(lg[i] - m) : 0.f;
            ssum += lg[i];
        }
        ssum += __shfl_xor(ssum, 1);
        ssum += __shfl_xor(ssum, 2);
        ssum += __shfl_xor(ssum, 4);
        float inv = 1.f / ssum;
        #pragma unroll
        for (int i = 0; i < 7; ++i) {
            int j = t8 + i * 8;
            if (j < 49) attn_s[q * 52 + j] = lg[i] * inv;   // wave-local
        }

        // PV: lane t8 accumulates dims [t8*4, t8*4+4) of head hd
        const int sv = hd * 4 + (t8 >> 1);
        const int off = (t8 & 1) * 4;
        float o0 = 0.f, o1 = 0.f, o2 = 0.f, o3 = 0.f;
        #pragma unroll
        for (int j = 0; j < 49; ++j) {
            const int p = j / 7, qq = j % 7;   // compile-time
            int lp = base_lp + p * HALO_W + qq;
            float a = attn_s[q * 52 + j];
            uint2 vu = *(const uint2*)&V_s[lp * 128 + (sv ^ (lp & 7)) * 8 + off];
            o0 += a * bflo(vu.x); o1 += a * bfhi(vu.x);
            o2 += a * bflo(vu.y); o3 += a * bfhi(vu.y);
        }
        union { ushort s[4]; uint2 u; } w;
        w.s[0] = f2bf(o0); w.s[1] = f2bf(o1); w.s[2] = f2bf(o2); w.s[3] = f2bf(o3);
        *(uint2*)&AO_s[q * 128 + (sv ^ (q & 7)) * 8 + off] = w.u;
    }
    __syncthreads();

    // ---- proj: out(32x128) = AO @ Wp^T + b_proj ----
    const int wid = tid >> 6, lane = tid & 63;
    const int l15 = lane & 15, l4 = lane >> 4;
    const int wr = wid >> 1, wc = wid & 1;

    f32x4 pacc[4] = {};
    #pragma unroll
    for (int ks = 0; ks < 4; ++ks) {
        int arow = wr * 16 + l15;
        short8 af = *(const short8*)&AO_s[arow * 128 + ((ks * 4 + l4) ^ (arow & 7)) * 8];
        #pragma unroll
        for (int fn = 0; fn < 4; ++fn) {
            int brow = wc * 64 + fn * 16 + l15;
            short8 bf = *(const short8*)(Wp_t + (size_t)brow * 128 + (ks * 4 + l4) * 8);
            pacc[fn] = __builtin_amdgcn_mfma_f32_16x16x32_bf16(af, bf, pacc[fn], 0, 0, 0);
        }
    }
    #pragma unroll
    for (int fn = 0; fn < 4; ++fn) {
        int col = wc * 64 + fn * 16 + l15;
        float bc = b_proj[col];
        #pragma unroll
        for (int reg = 0; reg < 4; ++reg) {
            int q2 = wr * 16 + l4 * 4 + reg;
            int oh = h0 + (q2 >> 3), ow = w0 + (q2 & 7);
            out[(size_t)((b << 12) + (oh << 6) + ow) * 128 + col] = pacc[fn][reg] + bc;
        }
    }
}

extern "C" void kernel_launch(void* const* d_in, const int* in_sizes, int n_in,
                              void* d_out, int out_size, void* d_ws, size_t ws_size,
                              hipStream_t stream)
{
    const float* x      = (const float*)d_in[0];
    const float* w_qkv  = (const float*)d_in[1];
    const float* b_qkv  = (const float*)d_in[2];
    const float* rpb    = (const float*)d_in[3];
    const float* w_proj = (const float*)d_in[4];
    const float* b_proj = (const float*)d_in[5];
    float* out = (float*)d_out;

    const int M = BB * HH * WW;                   // 8192
    ushort* qkv  = (ushort*)d_ws;                 // M x 384 bf16
    ushort* Wp_t = qkv + (size_t)M * 384;         // 128 x 128 bf16

    qkv_gemm_kernel<<<dim3(128, 2), 256, 0, stream>>>(
        x, w_qkv, b_qkv, w_proj, qkv, Wp_t);

    natten_proj_kernel<<<256, 256, 0, stream>>>(
        qkv, rpb, Wp_t, b_proj, out);
}